// Round 4
// baseline (249.566 us; speedup 1.0000x reference)
//
#include <hip/hip_runtime.h>
#include <hip/hip_bf16.h>
#include <stdint.h>

typedef __attribute__((ext_vector_type(8))) short bf16x8;
typedef __attribute__((ext_vector_type(4))) float f32x4;
#define MFMA16 __builtin_amdgcn_mfma_f32_16x16x32_bf16

__device__ __forceinline__ float celu_f(float x) {
    return x > 0.f ? x : 0.1f * (__expf(x * 10.f) - 1.f);
}
__device__ __forceinline__ uint16_t bfb(float x) {
    __hip_bfloat16 h = __float2bfloat16(x);
    return *reinterpret_cast<const uint16_t*>(&h);
}
__device__ __forceinline__ uint32_t pack2(float lo, float hi) {
    return (uint32_t)bfb(lo) | ((uint32_t)bfb(hi) << 16);
}
__device__ __forceinline__ bf16x8 cvt8(float4 a, float4 b) {
    bf16x8 r;
    r[0] = (short)bfb(a.x); r[1] = (short)bfb(a.y); r[2] = (short)bfb(a.z); r[3] = (short)bfb(a.w);
    r[4] = (short)bfb(b.x); r[5] = (short)bfb(b.y); r[6] = (short)bfb(b.z); r[7] = (short)bfb(b.w);
    return r;
}

// ---------------- pass 0: split+swizzle weights into A-fragment order ----------------
// out element pair-block: [(e*MB+mb)*KB+kb][lane l][ hi[8] | lo[8] ]  (bf16)
// A-frag mapping: m = mb*16 + l%16 ; k = kb*32 + (l/16)*8 + j
template <int DIN, int DOUT>
__global__ void wsplit_kernel(const float* __restrict__ W, __hip_bfloat16* __restrict__ out) {
    constexpr int MB = DOUT / 16, KB = DIN / 32;
    constexpr int PER_E = MB * KB * 512;
    const int idx = blockIdx.x * 256 + threadIdx.x;
    if (idx >= 4 * PER_E) return;
    const int e = idx / PER_E;
    int r = idx % PER_E;
    const int mb = r / (KB * 512); r %= KB * 512;
    const int kb = r / 512;        r %= 512;
    const int l = r / 8, j = r % 8;
    const int m = mb * 16 + (l % 16);
    const int k = kb * 32 + (l / 16) * 8 + j;
    const float w = W[((size_t)e * DIN + k) * DOUT + m];
    const __hip_bfloat16 hi = __float2bfloat16(w);
    const float lof = w - __bfloat162float(hi);
    const size_t base = (size_t)(idx / 8) * 16;
    out[base + j]     = hi;
    out[base + 8 + j] = __float2bfloat16(lof);
}

// ---------------- pass 1: bucket atoms by species ----------------
__global__ void bucket_kernel(const int* __restrict__ species, int N,
                              int* __restrict__ counts, int* __restrict__ bidx) {
    __shared__ int lcount[4];
    __shared__ int lbase[4];
    const int t = threadIdx.x;
    if (t < 4) lcount[t] = 0;
    __syncthreads();
    const int n = blockIdx.x * blockDim.x + t;
    int sp = 0, lo = 0;
    const bool valid = (n < N);
    if (valid) {
        sp = species[n];
        lo = atomicAdd(&lcount[sp], 1);
    }
    __syncthreads();
    if (t < 4) lbase[t] = atomicAdd(&counts[t], lcount[t]);
    __syncthreads();
    if (valid) bidx[sp * N + lbase[sp] + lo] = n;
}

// ---------------- LDS-input MFMA layer ----------------
template <int MB, int KB, int INS>
__device__ __forceinline__ void lds_layer(const __hip_bfloat16* Hin, const bf16x8* wpe,
                                          int l, f32x4 (*acc)[2]) {
    const int a = l & 15, q = l >> 4;
#pragma unroll
    for (int kb = 0; kb < KB; ++kb) {
        bf16x8 h0 = *(const bf16x8*)(Hin + a * INS + kb * 32 + q * 8);
        bf16x8 h1 = *(const bf16x8*)(Hin + (16 + a) * INS + kb * 32 + q * 8);
#pragma unroll
        for (int mb = 0; mb < MB; ++mb) {
            const size_t off = ((size_t)(mb * KB + kb) * 64 + l) * 2;
            bf16x8 whi = wpe[off], wlo = wpe[off + 1];
            acc[mb][0] = MFMA16(whi, h0, acc[mb][0], 0, 0, 0);
            acc[mb][0] = MFMA16(wlo, h0, acc[mb][0], 0, 0, 0);
            acc[mb][1] = MFMA16(whi, h1, acc[mb][1], 0, 0, 0);
            acc[mb][1] = MFMA16(wlo, h1, acc[mb][1], 0, 0, 0);
        }
    }
}

// ---------------- bias + CELU + bf16 pack to LDS ----------------
template <int MB, int OUTS>
__device__ __forceinline__ void epi(const f32x4 (*acc)[2], const float* bb,
                                    __hip_bfloat16* Hout, int l) {
    const int a = l & 15, fr = (l >> 4) * 4;
#pragma unroll
    for (int mb = 0; mb < MB; ++mb) {
        const float4 bl = *(const float4*)(bb + mb * 16 + fr);
        const float bv[4] = {bl.x, bl.y, bl.z, bl.w};
#pragma unroll
        for (int c = 0; c < 2; ++c) {
            const float o0 = celu_f(acc[mb][c][0] + bv[0]);
            const float o1 = celu_f(acc[mb][c][1] + bv[1]);
            const float o2 = celu_f(acc[mb][c][2] + bv[2]);
            const float o3 = celu_f(acc[mb][c][3] + bv[3]);
            uint2 pp;
            pp.x = pack2(o0, o1);
            pp.y = pack2(o2, o3);
            *(uint2*)(Hout + (c * 16 + a) * OUTS + mb * 16 + fr) = pp;
        }
    }
}

// ---------------- pass 2: fused MFMA MLP, 4 independent waves x 32 atoms ----------------
// H1 (32x160) and H2 (32x128) share ONE per-wave 32x168 buffer: layer-2's
// epilogue writes are issued strictly after all layer-2 ds_reads of H1, and
// per-wave LDS ops complete in order (lgkmcnt), so aliasing is safe.
// LDS/block = 4 * 32*168*2 B = 43008 B -> 3 blocks/CU (was 77824 -> 2).
__global__ __launch_bounds__(256, 2) void mlp_mfma_kernel(
    const float* __restrict__ aev, const int* __restrict__ bidx,
    const int* __restrict__ counts, int N, int gridx,
    const __hip_bfloat16* __restrict__ wsw1, const float* __restrict__ b1,
    const __hip_bfloat16* __restrict__ wsw2, const float* __restrict__ b2,
    const __hip_bfloat16* __restrict__ wsw3, const float* __restrict__ b3,
    const float* __restrict__ W4, const float* __restrict__ b4,
    float* __restrict__ partials) {
    __shared__ __align__(16) __hip_bfloat16 lds[4][32 * 168];
    const int e = blockIdx.y, tile = blockIdx.x, t = threadIdx.x;
    const int w = t >> 6, l = t & 63;
    const int pslot = (e * gridx + tile) * 4 + w;
    const int cnt = counts[e];
    const int wbase = tile * 128 + w * 32;
    if (wbase >= cnt) {                 // wave-uniform exit; kernel has no barriers
        if (l == 0) partials[pslot] = 0.f;
        return;
    }
    const int a = l & 15, q = l >> 4;
    const int g0 = wbase + a, g1 = wbase + 16 + a;
    const bool v0g = g0 < cnt, v1g = g1 < cnt;
    const int i0 = bidx[e * N + (v0g ? g0 : wbase)];
    const int i1 = bidx[e * N + (v1g ? g1 : wbase)];
    const float* row0 = aev + (size_t)i0 * 384 + q * 8;
    const float* row1 = aev + (size_t)i1 * 384 + q * 8;

    __hip_bfloat16* H = &lds[w][0];     // H1 then (aliased) H2

    // ---- layer 1: X[32x384] -> 160
    f32x4 acc1[10][2] = {};
    {
        const bf16x8* wp = (const bf16x8*)wsw1 + (size_t)e * 10 * 12 * 128;
#pragma unroll 2
        for (int kb = 0; kb < 12; ++kb) {
            const float4 xa = *(const float4*)(row0 + kb * 32);
            const float4 xb = *(const float4*)(row0 + kb * 32 + 4);
            const float4 xc = *(const float4*)(row1 + kb * 32);
            const float4 xd = *(const float4*)(row1 + kb * 32 + 4);
            const bf16x8 x0 = cvt8(xa, xb), x1 = cvt8(xc, xd);
            const bf16x8* wk = wp + ((size_t)kb * 64 + l) * 2;
#pragma unroll
            for (int mb = 0; mb < 10; ++mb) {
                const bf16x8 whi = wk[0], wlo = wk[1];
                wk += 12 * 128;         // next mb (KB*64*2 bf16x8)
                acc1[mb][0] = MFMA16(whi, x0, acc1[mb][0], 0, 0, 0);
                acc1[mb][0] = MFMA16(wlo, x0, acc1[mb][0], 0, 0, 0);
                acc1[mb][1] = MFMA16(whi, x1, acc1[mb][1], 0, 0, 0);
                acc1[mb][1] = MFMA16(wlo, x1, acc1[mb][1], 0, 0, 0);
            }
        }
    }
    epi<10, 168>(acc1, b1 + e * 160, H, l);

    // ---- layer 2: 160 -> 128 (reads H1, then writes H2 over the same buffer)
    f32x4 acc2[8][2] = {};
    lds_layer<8, 5, 168>(H, (const bf16x8*)wsw2 + (size_t)e * 8 * 5 * 128, l, acc2);
    epi<8, 168>(acc2, b2 + e * 128, H, l);

    // ---- layer 3: 128 -> 96 (reads H2; no LDS write — epilogue fused below)
    f32x4 acc3[6][2] = {};
    lds_layer<6, 4, 168>(H, (const bf16x8*)wsw3 + (size_t)e * 6 * 4 * 128, l, acc3);

    // ---- layer 3 epilogue fused with layer 4 (96 -> 1) dot
    const int fr = q * 4;
    float en0 = 0.f, en1 = 0.f;
#pragma unroll
    for (int mb = 0; mb < 6; ++mb) {
        const float4 bl = *(const float4*)(b3 + e * 96 + mb * 16 + fr);
        const float4 wv = *(const float4*)(W4 + e * 96 + mb * 16 + fr);
        const float bv[4] = {bl.x, bl.y, bl.z, bl.w};
        const float wb[4] = {wv.x, wv.y, wv.z, wv.w};
#pragma unroll
        for (int r = 0; r < 4; ++r) {
            en0 += celu_f(acc3[mb][0][r] + bv[r]) * wb[r];
            en1 += celu_f(acc3[mb][1][r] + bv[r]) * wb[r];
        }
    }
    en0 += __shfl_xor(en0, 16); en0 += __shfl_xor(en0, 32);
    en1 += __shfl_xor(en1, 16); en1 += __shfl_xor(en1, 32);
    const float b4e = b4[e];
    float p = 0.f;
    if (l < 16) p = (v0g ? en0 + b4e : 0.f) + (v1g ? en1 + b4e : 0.f);
#pragma unroll
    for (int off = 1; off <= 32; off <<= 1) p += __shfl_xor(p, off);
    if (l == 0) partials[pslot] = p;
}

// ---------------- pass 3: deterministic tree reduce ----------------
__global__ void reduce_kernel(const float* __restrict__ partials, int n,
                              float* __restrict__ out) {
    __shared__ float wsum[4];
    const int t = threadIdx.x;
    float s = 0.f;
    for (int i = t; i < n; i += 256) s += partials[i];
#pragma unroll
    for (int off = 32; off; off >>= 1) s += __shfl_down(s, off);
    if ((t & 63) == 0) wsum[t >> 6] = s;
    __syncthreads();
    if (t == 0) out[0] = wsum[0] + wsum[1] + wsum[2] + wsum[3];
}

extern "C" void kernel_launch(void* const* d_in, const int* in_sizes, int n_in,
                              void* d_out, int out_size, void* d_ws, size_t ws_size,
                              hipStream_t stream) {
    const float* aev     = (const float*)d_in[0];
    const int*   species = (const int*)d_in[1];
    const float* W1 = (const float*)d_in[2];
    const float* b1 = (const float*)d_in[3];
    const float* W2 = (const float*)d_in[4];
    const float* b2 = (const float*)d_in[5];
    const float* W3 = (const float*)d_in[6];
    const float* b3 = (const float*)d_in[7];
    const float* W4 = (const float*)d_in[8];
    const float* b4 = (const float*)d_in[9];
    float* out = (float*)d_out;

    const int N = in_sizes[1];
    const int gridx = (N + 127) / 128;

    // ws layout (all 256-aligned)
    char* ws = (char*)d_ws;
    int* counts = (int*)ws;
    float* partials = (float*)(ws + 256);
    size_t off = 256 + (size_t)gridx * 16 * sizeof(float);
    off = (off + 255) & ~(size_t)255;
    __hip_bfloat16* wsw1 = (__hip_bfloat16*)(ws + off); off += (size_t)4 * 384 * 160 * 2 * 2;
    __hip_bfloat16* wsw2 = (__hip_bfloat16*)(ws + off); off += (size_t)4 * 160 * 128 * 2 * 2;
    __hip_bfloat16* wsw3 = (__hip_bfloat16*)(ws + off); off += (size_t)4 * 128 * 96 * 2 * 2;
    int* bidx = (int*)(ws + off);

    hipMemsetAsync(d_ws, 0, 16, stream);

    wsplit_kernel<384, 160><<<(4 * 384 * 160 + 255) / 256, 256, 0, stream>>>(W1, wsw1);
    wsplit_kernel<160, 128><<<(4 * 160 * 128 + 255) / 256, 256, 0, stream>>>(W2, wsw2);
    wsplit_kernel<128, 96><<<(4 * 128 * 96 + 255) / 256, 256, 0, stream>>>(W3, wsw3);

    bucket_kernel<<<(N + 255) / 256, 256, 0, stream>>>(species, N, counts, bidx);

    dim3 grid(gridx, 4);
    mlp_mfma_kernel<<<grid, 256, 0, stream>>>(aev, bidx, counts, N, gridx,
                                              wsw1, b1, wsw2, b2, wsw3, b3, W4, b4,
                                              partials);

    reduce_kernel<<<1, 256, 0, stream>>>(partials, gridx * 16, out);
}

// Round 5
// 204.821 us; speedup vs baseline: 1.2185x; 1.2185x over previous
//
#include <hip/hip_runtime.h>
#include <hip/hip_bf16.h>
#include <stdint.h>

typedef __attribute__((ext_vector_type(8))) short bf16x8;
typedef __attribute__((ext_vector_type(4))) float f32x4;
#define MFMA16 __builtin_amdgcn_mfma_f32_16x16x32_bf16

__device__ __forceinline__ float celu_f(float x) {
    return x > 0.f ? x : 0.1f * (__expf(x * 10.f) - 1.f);
}
__device__ __forceinline__ uint16_t bfb(float x) {
    __hip_bfloat16 h = __float2bfloat16(x);
    return *reinterpret_cast<const uint16_t*>(&h);
}
__device__ __forceinline__ uint32_t pack2(float lo, float hi) {
    return (uint32_t)bfb(lo) | ((uint32_t)bfb(hi) << 16);
}
__device__ __forceinline__ bf16x8 cvt8(float4 a, float4 b) {
    bf16x8 r;
    r[0] = (short)bfb(a.x); r[1] = (short)bfb(a.y); r[2] = (short)bfb(a.z); r[3] = (short)bfb(a.w);
    r[4] = (short)bfb(b.x); r[5] = (short)bfb(b.y); r[6] = (short)bfb(b.z); r[7] = (short)bfb(b.w);
    return r;
}
// async global -> LDS, 16B per lane (dest = uniform base + lane*16)
__device__ __forceinline__ void gload16(const void* g, void* l) {
    __builtin_amdgcn_global_load_lds(
        (const __attribute__((address_space(1))) unsigned int*)g,
        (__attribute__((address_space(3))) unsigned int*)l, 16, 0, 0);
}

// ---------------- pass 0: split+swizzle weights into A-fragment order ----------------
// pair-block (e,mb,kb): 2048 B = [lane l][ hi 16B | lo 16B ]
// A-frag mapping: m = mb*16 + l%16 ; k = kb*32 + (l/16)*8 + j
template <int DIN, int DOUT>
__global__ void wsplit_kernel(const float* __restrict__ W, __hip_bfloat16* __restrict__ out) {
    constexpr int MB = DOUT / 16, KB = DIN / 32;
    constexpr int PER_E = MB * KB * 512;
    const int idx = blockIdx.x * 256 + threadIdx.x;
    if (idx >= 4 * PER_E) return;
    const int e = idx / PER_E;
    int r = idx % PER_E;
    const int mb = r / (KB * 512); r %= KB * 512;
    const int kb = r / 512;        r %= 512;
    const int l = r / 8, j = r % 8;
    const int m = mb * 16 + (l % 16);
    const int k = kb * 32 + (l / 16) * 8 + j;
    const float w = W[((size_t)e * DIN + k) * DOUT + m];
    const __hip_bfloat16 hi = __float2bfloat16(w);
    const float lof = w - __bfloat162float(hi);
    const size_t base = (size_t)(idx / 8) * 16;
    out[base + j]     = hi;
    out[base + 8 + j] = __float2bfloat16(lof);
}

// ---------------- pass 1: bucket atoms by species ----------------
__global__ void bucket_kernel(const int* __restrict__ species, int N,
                              int* __restrict__ counts, int* __restrict__ bidx) {
    __shared__ int lcount[4];
    __shared__ int lbase[4];
    const int t = threadIdx.x;
    if (t < 4) lcount[t] = 0;
    __syncthreads();
    const int n = blockIdx.x * blockDim.x + t;
    int sp = 0, lo = 0;
    const bool valid = (n < N);
    if (valid) {
        sp = species[n];
        lo = atomicAdd(&lcount[sp], 1);
    }
    __syncthreads();
    if (t < 4) lbase[t] = atomicAdd(&counts[t], lcount[t]);
    __syncthreads();
    if (valid) bidx[sp * N + lbase[sp] + lo] = n;
}

// ---------------- cooperative weight staging (flat step schedule) ----------------
// steps: L1 = 0..23 (kb=s/2, half=s&1, 5 mb/half), L2 = 24..33 (4 mb/half),
//        L3 = 34..41 (3 mb/half). Unit u = mb_local*2 + (hi/lo), 1KB each.
__device__ __forceinline__ void stage_for(int s, int e, int w, int l,
                                          const char* w1b, const char* w2b,
                                          const char* w3b, char* slot) {
    if (s >= 42) return;
    const int half = s & 1;
    if (s < 24) {
        const int kb = s >> 1;
        for (int u = w; u < 10; u += 4) {
            const int mb = half * 5 + (u >> 1), h = u & 1;
            const char* src = w1b + ((((size_t)e * 10 + mb) * 12 + kb) << 11) + l * 32 + h * 16;
            gload16(src, slot + u * 1024);
        }
    } else if (s < 34) {
        const int kb = (s - 24) >> 1;
        for (int u = w; u < 8; u += 4) {
            const int mb = half * 4 + (u >> 1), h = u & 1;
            const char* src = w2b + ((((size_t)e * 8 + mb) * 5 + kb) << 11) + l * 32 + h * 16;
            gload16(src, slot + u * 1024);
        }
    } else {
        const int kb = (s - 34) >> 1;
        for (int u = w; u < 6; u += 4) {
            const int mb = half * 3 + (u >> 1), h = u & 1;
            const char* src = w3b + ((((size_t)e * 6 + mb) * 4 + kb) << 11) + l * 32 + h * 16;
            gload16(src, slot + u * 1024);
        }
    }
}

// consume MBH mb-units from an LDS slot (contiguous 16B/lane -> conflict-free)
template <int MBH>
__device__ __forceinline__ void consume_slot(const char* slot, int l,
                                             bf16x8 x0, bf16x8 x1, f32x4 (*acc)[2]) {
#pragma unroll
    for (int i = 0; i < MBH; ++i) {
        const bf16x8 whi = *(const bf16x8*)(slot + i * 2048 + l * 16);
        const bf16x8 wlo = *(const bf16x8*)(slot + i * 2048 + 1024 + l * 16);
        acc[i][0] = MFMA16(whi, x0, acc[i][0], 0, 0, 0);
        acc[i][0] = MFMA16(wlo, x0, acc[i][0], 0, 0, 0);
        acc[i][1] = MFMA16(whi, x1, acc[i][1], 0, 0, 0);
        acc[i][1] = MFMA16(wlo, x1, acc[i][1], 0, 0, 0);
    }
}

// ---------------- bias + CELU + bf16 pack to LDS ----------------
template <int MB, int OUTS>
__device__ __forceinline__ void epi(const f32x4 (*acc)[2], const float* bb,
                                    __hip_bfloat16* Hout, int l) {
    const int a = l & 15, fr = (l >> 4) * 4;
#pragma unroll
    for (int mb = 0; mb < MB; ++mb) {
        const float4 bl = *(const float4*)(bb + mb * 16 + fr);
        const float bv[4] = {bl.x, bl.y, bl.z, bl.w};
#pragma unroll
        for (int c = 0; c < 2; ++c) {
            const float o0 = celu_f(acc[mb][c][0] + bv[0]);
            const float o1 = celu_f(acc[mb][c][1] + bv[1]);
            const float o2 = celu_f(acc[mb][c][2] + bv[2]);
            const float o3 = celu_f(acc[mb][c][3] + bv[3]);
            uint2 pp;
            pp.x = pack2(o0, o1);
            pp.y = pack2(o2, o3);
            *(uint2*)(Hout + (c * 16 + a) * OUTS + mb * 16 + fr) = pp;
        }
    }
}

// ---------------- pass 2: fused MFMA MLP, LDS-staged weights ----------------
// LDS: H 4*32*168*2 = 43008 B + W ring 2*10240 = 20480 B -> 63488 B -> 2 blocks/CU
__global__ __launch_bounds__(256, 2) void mlp_mfma_kernel(
    const float* __restrict__ aev, const int* __restrict__ bidx,
    const int* __restrict__ counts, int N, int gridx,
    const __hip_bfloat16* __restrict__ wsw1, const float* __restrict__ b1,
    const __hip_bfloat16* __restrict__ wsw2, const float* __restrict__ b2,
    const __hip_bfloat16* __restrict__ wsw3, const float* __restrict__ b3,
    const float* __restrict__ W4, const float* __restrict__ b4,
    float* __restrict__ partials) {
    __shared__ __align__(16) __hip_bfloat16 Hlds[4][32 * 168];
    __shared__ __align__(16) char Wslot[2][10240];
    const int e = blockIdx.y, tile = blockIdx.x, t = threadIdx.x;
    const int w = t >> 6, l = t & 63;
    const int pslot = (e * gridx + tile) * 4 + w;
    const int cnt = counts[e];
    if (tile * 128 >= cnt) {            // block-uniform exit, before any barrier
        if (l == 0) partials[pslot] = 0.f;
        return;
    }
    const int wbase = tile * 128 + w * 32;
    const int a = l & 15, q = l >> 4;
    const int g0 = wbase + a, g1 = wbase + 16 + a;
    const bool v0g = g0 < cnt, v1g = g1 < cnt;
    const int i0 = bidx[e * N + min(g0, cnt - 1)];
    const int i1 = bidx[e * N + min(g1, cnt - 1)];
    const float* row0 = aev + (size_t)i0 * 384 + q * 8;
    const float* row1 = aev + (size_t)i1 * 384 + q * 8;

    const char* w1b = (const char*)wsw1;
    const char* w2b = (const char*)wsw2;
    const char* w3b = (const char*)wsw3;
    __hip_bfloat16* H = &Hlds[w][0];    // H1 then (aliased) H2; per-wave, in-order LDS

    // prologue: stage step 0, preload X kb=0
    float4 na = *(const float4*)(row0);
    float4 nb = *(const float4*)(row0 + 4);
    float4 nc = *(const float4*)(row1);
    float4 nd = *(const float4*)(row1 + 4);
    stage_for(0, e, w, l, w1b, w2b, w3b, &Wslot[0][0]);
    __syncthreads();

    int step = 0;

    // ---- layer 1: X[32x384] -> 160
    f32x4 acc1[10][2] = {};
#pragma unroll 1
    for (int kb = 0; kb < 12; ++kb) {
        const bf16x8 x0 = cvt8(na, nb), x1 = cvt8(nc, nd);
        // half 0 (mb 0..4)
        stage_for(step + 1, e, w, l, w1b, w2b, w3b, &Wslot[(step + 1) & 1][0]);
        consume_slot<5>(&Wslot[step & 1][0], l, x0, x1, &acc1[0]);
        __syncthreads(); ++step;
        // prefetch X for kb+1 (named regs; survives one barrier)
        if (kb < 11) {
            na = *(const float4*)(row0 + (kb + 1) * 32);
            nb = *(const float4*)(row0 + (kb + 1) * 32 + 4);
            nc = *(const float4*)(row1 + (kb + 1) * 32);
            nd = *(const float4*)(row1 + (kb + 1) * 32 + 4);
        }
        // half 1 (mb 5..9)
        stage_for(step + 1, e, w, l, w1b, w2b, w3b, &Wslot[(step + 1) & 1][0]);
        consume_slot<5>(&Wslot[step & 1][0], l, x0, x1, &acc1[5]);
        __syncthreads(); ++step;
    }
    epi<10, 168>(acc1, b1 + e * 160, H, l);

    // ---- layer 2: 160 -> 128 (H1 from LDS)
    f32x4 acc2[8][2] = {};
#pragma unroll 1
    for (int kb = 0; kb < 5; ++kb) {
        const bf16x8 h0 = *(const bf16x8*)(H + a * 168 + kb * 32 + q * 8);
        const bf16x8 h1 = *(const bf16x8*)(H + (16 + a) * 168 + kb * 32 + q * 8);
        stage_for(step + 1, e, w, l, w1b, w2b, w3b, &Wslot[(step + 1) & 1][0]);
        consume_slot<4>(&Wslot[step & 1][0], l, h0, h1, &acc2[0]);
        __syncthreads(); ++step;
        stage_for(step + 1, e, w, l, w1b, w2b, w3b, &Wslot[(step + 1) & 1][0]);
        consume_slot<4>(&Wslot[step & 1][0], l, h0, h1, &acc2[4]);
        __syncthreads(); ++step;
    }
    epi<8, 168>(acc2, b2 + e * 128, H, l);   // alias H2 over H1 (in-order per wave)

    // ---- layer 3: 128 -> 96 (H2 from LDS; no LDS write)
    f32x4 acc3[6][2] = {};
#pragma unroll 1
    for (int kb = 0; kb < 4; ++kb) {
        const bf16x8 h0 = *(const bf16x8*)(H + a * 168 + kb * 32 + q * 8);
        const bf16x8 h1 = *(const bf16x8*)(H + (16 + a) * 168 + kb * 32 + q * 8);
        stage_for(step + 1, e, w, l, w1b, w2b, w3b, &Wslot[(step + 1) & 1][0]);
        consume_slot<3>(&Wslot[step & 1][0], l, h0, h1, &acc3[0]);
        __syncthreads(); ++step;
        stage_for(step + 1, e, w, l, w1b, w2b, w3b, &Wslot[(step + 1) & 1][0]);
        consume_slot<3>(&Wslot[step & 1][0], l, h0, h1, &acc3[3]);
        __syncthreads(); ++step;
    }

    // ---- layer 3 epilogue fused with layer 4 (96 -> 1) dot
    const int fr = q * 4;
    float en0 = 0.f, en1 = 0.f;
#pragma unroll
    for (int mb = 0; mb < 6; ++mb) {
        const float4 bl = *(const float4*)(b3 + e * 96 + mb * 16 + fr);
        const float4 wv = *(const float4*)(W4 + e * 96 + mb * 16 + fr);
        const float bv[4] = {bl.x, bl.y, bl.z, bl.w};
        const float wb[4] = {wv.x, wv.y, wv.z, wv.w};
#pragma unroll
        for (int r = 0; r < 4; ++r) {
            en0 += celu_f(acc3[mb][0][r] + bv[r]) * wb[r];
            en1 += celu_f(acc3[mb][1][r] + bv[r]) * wb[r];
        }
    }
    en0 += __shfl_xor(en0, 16); en0 += __shfl_xor(en0, 32);
    en1 += __shfl_xor(en1, 16); en1 += __shfl_xor(en1, 32);
    const float b4e = b4[e];
    float p = 0.f;
    if (l < 16) p = (v0g ? en0 + b4e : 0.f) + (v1g ? en1 + b4e : 0.f);
#pragma unroll
    for (int off = 1; off <= 32; off <<= 1) p += __shfl_xor(p, off);
    if (l == 0) partials[pslot] = p;
}

// ---------------- pass 3: deterministic tree reduce ----------------
__global__ void reduce_kernel(const float* __restrict__ partials, int n,
                              float* __restrict__ out) {
    __shared__ float wsum[4];
    const int t = threadIdx.x;
    float s = 0.f;
    for (int i = t; i < n; i += 256) s += partials[i];
#pragma unroll
    for (int off = 32; off; off >>= 1) s += __shfl_down(s, off);
    if ((t & 63) == 0) wsum[t >> 6] = s;
    __syncthreads();
    if (t == 0) out[0] = wsum[0] + wsum[1] + wsum[2] + wsum[3];
}

extern "C" void kernel_launch(void* const* d_in, const int* in_sizes, int n_in,
                              void* d_out, int out_size, void* d_ws, size_t ws_size,
                              hipStream_t stream) {
    const float* aev     = (const float*)d_in[0];
    const int*   species = (const int*)d_in[1];
    const float* W1 = (const float*)d_in[2];
    const float* b1 = (const float*)d_in[3];
    const float* W2 = (const float*)d_in[4];
    const float* b2 = (const float*)d_in[5];
    const float* W3 = (const float*)d_in[6];
    const float* b3 = (const float*)d_in[7];
    const float* W4 = (const float*)d_in[8];
    const float* b4 = (const float*)d_in[9];
    float* out = (float*)d_out;

    const int N = in_sizes[1];
    const int gridx = (N + 127) / 128;

    // ws layout (all 256-aligned)
    char* ws = (char*)d_ws;
    int* counts = (int*)ws;
    float* partials = (float*)(ws + 256);
    size_t off = 256 + (size_t)gridx * 16 * sizeof(float);
    off = (off + 255) & ~(size_t)255;
    __hip_bfloat16* wsw1 = (__hip_bfloat16*)(ws + off); off += (size_t)4 * 384 * 160 * 2 * 2;
    __hip_bfloat16* wsw2 = (__hip_bfloat16*)(ws + off); off += (size_t)4 * 160 * 128 * 2 * 2;
    __hip_bfloat16* wsw3 = (__hip_bfloat16*)(ws + off); off += (size_t)4 * 128 * 96 * 2 * 2;
    int* bidx = (int*)(ws + off);

    hipMemsetAsync(d_ws, 0, 16, stream);

    wsplit_kernel<384, 160><<<(4 * 384 * 160 + 255) / 256, 256, 0, stream>>>(W1, wsw1);
    wsplit_kernel<160, 128><<<(4 * 160 * 128 + 255) / 256, 256, 0, stream>>>(W2, wsw2);
    wsplit_kernel<128, 96><<<(4 * 128 * 96 + 255) / 256, 256, 0, stream>>>(W3, wsw3);

    bucket_kernel<<<(N + 255) / 256, 256, 0, stream>>>(species, N, counts, bidx);

    dim3 grid(gridx, 4);
    mlp_mfma_kernel<<<grid, 256, 0, stream>>>(aev, bidx, counts, N, gridx,
                                              wsw1, b1, wsw2, b2, wsw3, b3, W4, b4,
                                              partials);

    reduce_kernel<<<1, 256, 0, stream>>>(partials, gridx * 16, out);
}